// Round 3
// baseline (96.366 us; speedup 1.0000x reference)
//
#include <hip/hip_runtime.h>

// S4D real: y[l,c] = sum_s w[c,s] * h_s[l],  h_s[l] = x[l,c] + r[c,s]*h_s[l-1]
// Blocked parallel scan over L:
//   k_params : precompute r = exp(A*dt), w = C*Bd in coalesced [s][c] layout
//   k_local  : per-chunk scan with zero carry, store chunk-end states
//   k_combine: carry prefix over chunks (batched loads -> register prefix)
//   k_scan_out: seeded re-scan + y = sum_s w*h
//
// R3 change: __launch_bounds__(64, 1) on the scan kernels. R1 profile showed
// VGPR_Count=112 while the live set (r[64]+w[64]+h[64]+acc) needs ~210 regs
// -> massive scratch spill in the inner loop. (64,1) lets the allocator use
// the full unified 512-VGPR file; 1 wave/SIMD is fine (128 indep FMAs/step).

namespace {

constexpr int L_ = 4096;
constexpr int CH_ = 512;
constexpr int S_ = 64;
constexpr float DT = 1.0f / 4096.0f;
constexpr int SC = S_ * CH_;  // 32768

// ---------------- Kernel P: parameter precompute ----------------------------
// One thread per (s,c); tid = s*CH + c. Gathers lognegA/B/C ([c][s] layout),
// writes r/w in [s][c] layout so scan kernels load them coalesced.
__global__ void k_params(const float* __restrict__ lognegA,
                         const float* __restrict__ B,
                         const float* __restrict__ C,
                         float* __restrict__ rt, float* __restrict__ wt) {
  const int tid = blockIdx.x * blockDim.x + threadIdx.x;  // s*CH + c
  const int s = tid >> 9;
  const int c = tid & (CH_ - 1);
  const int i = c * S_ + s;
  const float A = -expf(lognegA[i]);
  const float r = expf(A * DT);
  rt[tid] = r;
  wt[tid] = C[i] * ((r - 1.0f) * B[i] / A);
}

// ---------------- Kernel A: local chunk-end states (zero carry-in) ----------
// grid = (CH/64, NC), block = 64. lane -> channel. carry layout [k][s][c].
template <int T>
__global__ __launch_bounds__(64, 1) void k_local(const float* __restrict__ x,
                                                 const float* __restrict__ rt,
                                                 float* __restrict__ carry) {
  const int c = blockIdx.x * 64 + threadIdx.x;
  const int k = blockIdx.y;

  float r[S_], h[S_];
#pragma unroll
  for (int s = 0; s < S_; ++s) {
    r[s] = rt[s * CH_ + c];   // coalesced: lanes read contiguous c
    h[s] = 0.0f;
  }

  const float* xp = x + (size_t)k * T * CH_ + c;
#pragma unroll 4
  for (int l = 0; l < T; ++l) {
    const float xv = xp[l * CH_];
#pragma unroll
    for (int s = 0; s < S_; ++s) h[s] = fmaf(r[s], h[s], xv);
  }

  float* cp = carry + (size_t)k * SC + c;
#pragma unroll
  for (int s = 0; s < S_; ++s) cp[s * CH_] = h[s];
}

// ---------------- Kernel B: carry prefix over chunks ------------------------
// One thread per (s,c). In-place: carry[k] becomes carry-IN of chunk k.
// Loads are independent of the fma chain -> batch them to break the
// NC-step global-latency serialization.
template <int T, int NC>
__global__ void k_combine(const float* __restrict__ rt,
                          float* __restrict__ carry) {
  const int tid = blockIdx.x * blockDim.x + threadIdx.x;  // s*CH + c

  const float r = rt[tid];
  float rT = r;
#pragma unroll
  for (int t = 1; t < T; t <<= 1) rT *= rT;  // r^T (T is a power of two)

  constexpr int BATCH = (NC < 32) ? NC : 32;
  float state = 0.0f;  // carry-in of chunk 0
  for (int kb = 0; kb < NC; kb += BATCH) {
    float v[BATCH];
#pragma unroll
    for (int j = 0; j < BATCH; ++j) v[j] = carry[(size_t)(kb + j) * SC + tid];
#pragma unroll
    for (int j = 0; j < BATCH; ++j) {
      const float le = v[j];
      v[j] = state;                 // carry-in of chunk kb+j
      state = fmaf(rT, state, le);  // carry-in of next chunk
    }
#pragma unroll
    for (int j = 0; j < BATCH; ++j) carry[(size_t)(kb + j) * SC + tid] = v[j];
  }
}

// ---------------- Kernel C: seeded re-scan + output -------------------------
template <int T, bool USE_CARRY>
__global__ __launch_bounds__(64, 1) void k_scan_out(
    const float* __restrict__ x, const float* __restrict__ rt,
    const float* __restrict__ wt, const float* __restrict__ carry,
    float* __restrict__ y) {
  const int c = blockIdx.x * 64 + threadIdx.x;
  const int k = blockIdx.y;

  float r[S_], w[S_], h[S_];
#pragma unroll
  for (int s = 0; s < S_; ++s) {
    r[s] = rt[s * CH_ + c];
    w[s] = wt[s * CH_ + c];
    h[s] = USE_CARRY ? carry[(size_t)k * SC + s * CH_ + c] : 0.0f;
  }

  const float* xp = x + (size_t)k * T * CH_ + c;
  float* yp = y + (size_t)k * T * CH_ + c;

#pragma unroll 4
  for (int l = 0; l < T; ++l) {
    const float xv = xp[l * CH_];
    float acc[8] = {0, 0, 0, 0, 0, 0, 0, 0};
#pragma unroll
    for (int s = 0; s < S_; ++s) {
      h[s] = fmaf(r[s], h[s], xv);
      acc[s & 7] = fmaf(w[s], h[s], acc[s & 7]);
    }
    yp[l * CH_] = ((acc[0] + acc[4]) + (acc[2] + acc[6])) +
                  ((acc[1] + acc[5]) + (acc[3] + acc[7]));
  }
}

template <int T>
void launch_all(const float* x, const float* la, const float* B, const float* C,
                float* ws, float* y, hipStream_t stream) {
  constexpr int NC = L_ / T;
  float* carry = ws;
  float* rt = ws + (size_t)NC * SC;
  float* wt = rt + SC;

  k_params<<<SC / 256, 256, 0, stream>>>(la, B, C, rt, wt);
  dim3 g(CH_ / 64, NC);
  if (NC > 1) {
    k_local<T><<<g, 64, 0, stream>>>(x, rt, carry);
    k_combine<T, NC><<<SC / 256, 256, 0, stream>>>(rt, carry);
    k_scan_out<T, true><<<g, 64, 0, stream>>>(x, rt, wt, carry, y);
  } else {
    k_scan_out<T, false><<<g, 64, 0, stream>>>(x, rt, wt, carry, y);
  }
}

}  // namespace

extern "C" void kernel_launch(void* const* d_in, const int* in_sizes, int n_in,
                              void* d_out, int out_size, void* d_ws, size_t ws_size,
                              hipStream_t stream) {
  const float* x = (const float*)d_in[0];
  const float* la = (const float*)d_in[1];
  const float* B = (const float*)d_in[2];
  const float* C = (const float*)d_in[3];
  float* y = (float*)d_out;
  float* ws = (float*)d_ws;

  // Pick NC (power of two) so carry + r + w fit in workspace.
  int NC = 128;
  while (NC > 1 &&
         ((size_t)NC * SC + 2 * SC) * sizeof(float) > ws_size) NC >>= 1;

  switch (L_ / NC) {
    case 32:   launch_all<32>(x, la, B, C, ws, y, stream); break;
    case 64:   launch_all<64>(x, la, B, C, ws, y, stream); break;
    case 128:  launch_all<128>(x, la, B, C, ws, y, stream); break;
    case 256:  launch_all<256>(x, la, B, C, ws, y, stream); break;
    case 512:  launch_all<512>(x, la, B, C, ws, y, stream); break;
    case 1024: launch_all<1024>(x, la, B, C, ws, y, stream); break;
    case 2048: launch_all<2048>(x, la, B, C, ws, y, stream); break;
    default:   launch_all<4096>(x, la, B, C, ws, y, stream); break;
  }
}

// Round 5
// 93.816 us; speedup vs baseline: 1.0272x; 1.0272x over previous
//
#include <hip/hip_runtime.h>

// S4D real: y[l,c] = sum_s w[c,s] * h_s[l],  h_s[l] = x[l,c] + r[c,s]*h_s[l-1]
// Blocked parallel scan over L:
//   k_params : r = exp(A*dt), w = C*Bd in coalesced [s][c] layout
//   k_local_s: per-chunk scan, zero carry-in -> chunk-end states
//   k_combine: carry prefix over chunks (batched loads -> register prefix)
//   k_scan_s : seeded re-scan + y = sum_s w*h
//
// R5 change: split the S=64 state dim across the 4 waves of a 256-thread
// block (16 states/thread). R1 showed VGPR_Count=112 vs a ~210-reg live set
// for the monolithic version -> compiler re-loads r/w (or spills h) inside
// the hot loop. 16 states/thread needs ~60-80 VGPRs: no spills, 4 waves/SIMD.
// Partial y sums are combined across s-groups in LDS every 8 steps.

namespace {

constexpr int L_ = 4096;
constexpr int CH_ = 512;
constexpr int S_ = 64;
constexpr float DT = 1.0f / 4096.0f;
constexpr int SC = S_ * CH_;  // 32768
constexpr int SG = 16;        // states per thread (S_ / 4 waves)

// ---------------- Kernel P: parameter precompute ----------------------------
__global__ void k_params(const float* __restrict__ lognegA,
                         const float* __restrict__ B,
                         const float* __restrict__ C,
                         float* __restrict__ rt, float* __restrict__ wt) {
  const int tid = blockIdx.x * blockDim.x + threadIdx.x;  // s*CH + c
  const int s = tid >> 9;
  const int c = tid & (CH_ - 1);
  const int i = c * S_ + s;
  const float A = -expf(lognegA[i]);
  const float r = expf(A * DT);
  rt[tid] = r;
  wt[tid] = C[i] * ((r - 1.0f) * B[i] / A);
}

// ---------------- Kernel A: local chunk-end states (zero carry-in) ----------
// grid = NC*8, block = 256 (4 waves). wave g: states [16g,16g+16), lane: c.
template <int T>
__global__ __launch_bounds__(256) void k_local_s(const float* __restrict__ x,
                                                 const float* __restrict__ rt,
                                                 float* __restrict__ carry) {
  const int lane = threadIdx.x & 63;
  const int g = threadIdx.x >> 6;
  const int k = blockIdx.x >> 3;
  const int c = ((blockIdx.x & 7) << 6) + lane;
  const int s0 = g * SG;

  float r[SG], h[SG];
#pragma unroll
  for (int i = 0; i < SG; ++i) {
    r[i] = rt[(s0 + i) * CH_ + c];  // coalesced in c
    h[i] = 0.0f;
  }

  const float* xp = x + (size_t)k * T * CH_ + c;
#pragma unroll 8
  for (int l = 0; l < T; ++l) {
    const float xv = xp[l * CH_];
#pragma unroll
    for (int i = 0; i < SG; ++i) h[i] = fmaf(r[i], h[i], xv);
  }

#pragma unroll
  for (int i = 0; i < SG; ++i)
    carry[(size_t)k * SC + (s0 + i) * CH_ + c] = h[i];
}

// ---------------- Kernel B: carry prefix over chunks ------------------------
// One thread per (s,c). In-place: carry[k] becomes carry-IN of chunk k.
template <int T, int NC>
__global__ void k_combine(const float* __restrict__ rt,
                          float* __restrict__ carry) {
  const int tid = blockIdx.x * blockDim.x + threadIdx.x;  // s*CH + c

  float rT = rt[tid];
#pragma unroll
  for (int t = 1; t < T; t <<= 1) rT *= rT;  // r^T (T is a power of two)

  constexpr int BATCH = (NC < 32) ? NC : 32;
  float state = 0.0f;  // carry-in of chunk 0
  for (int kb = 0; kb < NC; kb += BATCH) {
    float v[BATCH];
#pragma unroll
    for (int j = 0; j < BATCH; ++j) v[j] = carry[(size_t)(kb + j) * SC + tid];
#pragma unroll
    for (int j = 0; j < BATCH; ++j) {
      const float le = v[j];
      v[j] = state;                 // carry-in of chunk kb+j
      state = fmaf(rT, state, le);  // carry-in of next chunk
    }
#pragma unroll
    for (int j = 0; j < BATCH; ++j) carry[(size_t)(kb + j) * SC + tid] = v[j];
  }
}

// ---------------- Kernel C: seeded re-scan + output -------------------------
// Same thread mapping as k_local_s. Each wave produces partial y over its 16
// states; partials for 8 consecutive l are merged across waves via LDS.
template <int T, bool USE_CARRY>
__global__ __launch_bounds__(256) void k_scan_s(const float* __restrict__ x,
                                                const float* __restrict__ rt,
                                                const float* __restrict__ wt,
                                                const float* __restrict__ carry,
                                                float* __restrict__ y) {
  __shared__ float lds[4][8][64];  // [s-group][j][lane]

  const int lane = threadIdx.x & 63;
  const int g = threadIdx.x >> 6;
  const int k = blockIdx.x >> 3;
  const int cb = (blockIdx.x & 7) << 6;
  const int c = cb + lane;
  const int s0 = g * SG;

  float r[SG], w[SG], h[SG];
#pragma unroll
  for (int i = 0; i < SG; ++i) {
    const int idx = (s0 + i) * CH_ + c;
    r[i] = rt[idx];
    w[i] = wt[idx];
    h[i] = USE_CARRY ? carry[(size_t)k * SC + idx] : 0.0f;
  }

  const float* xp = x + (size_t)k * T * CH_ + c;
  float* yp = y + (size_t)k * T * CH_;

  for (int l = 0; l < T; l += 8) {
    float part[8];
#pragma unroll
    for (int j = 0; j < 8; ++j) {
      const float xv = xp[(l + j) * CH_];
      float a0 = 0, a1 = 0, a2 = 0, a3 = 0;
#pragma unroll
      for (int i = 0; i < SG; i += 4) {
        h[i]     = fmaf(r[i],     h[i],     xv);
        h[i + 1] = fmaf(r[i + 1], h[i + 1], xv);
        h[i + 2] = fmaf(r[i + 2], h[i + 2], xv);
        h[i + 3] = fmaf(r[i + 3], h[i + 3], xv);
        a0 = fmaf(w[i],     h[i],     a0);
        a1 = fmaf(w[i + 1], h[i + 1], a1);
        a2 = fmaf(w[i + 2], h[i + 2], a2);
        a3 = fmaf(w[i + 3], h[i + 3], a3);
      }
      part[j] = (a0 + a1) + (a2 + a3);
    }

#pragma unroll
    for (int j = 0; j < 8; ++j) lds[g][j][lane] = part[j];
    __syncthreads();

    // 512 (j,lane) outputs, 256 threads -> 2 each; reads 2-way bank-aliased.
#pragma unroll
    for (int p = 0; p < 2; ++p) {
      const int idx = (int)threadIdx.x + p * 256;
      const int j = idx >> 6;
      const int ln = idx & 63;
      const float v = (lds[0][j][ln] + lds[1][j][ln]) +
                      (lds[2][j][ln] + lds[3][j][ln]);
      yp[(size_t)(l + j) * CH_ + cb + ln] = v;
    }
    __syncthreads();
  }
}

template <int T>
void launch_all(const float* x, const float* la, const float* B, const float* C,
                float* ws, float* y, hipStream_t stream) {
  constexpr int NC = L_ / T;
  float* carry = ws;
  float* rt = ws + (size_t)NC * SC;
  float* wt = rt + SC;

  k_params<<<SC / 256, 256, 0, stream>>>(la, B, C, rt, wt);
  if (NC > 1) {
    k_local_s<T><<<NC * 8, 256, 0, stream>>>(x, rt, carry);
    k_combine<T, NC><<<SC / 256, 256, 0, stream>>>(rt, carry);
    k_scan_s<T, true><<<NC * 8, 256, 0, stream>>>(x, rt, wt, carry, y);
  } else {
    k_scan_s<T, false><<<8, 256, 0, stream>>>(x, rt, wt, carry, y);
  }
}

}  // namespace

extern "C" void kernel_launch(void* const* d_in, const int* in_sizes, int n_in,
                              void* d_out, int out_size, void* d_ws, size_t ws_size,
                              hipStream_t stream) {
  const float* x = (const float*)d_in[0];
  const float* la = (const float*)d_in[1];
  const float* B = (const float*)d_in[2];
  const float* C = (const float*)d_in[3];
  float* y = (float*)d_out;
  float* ws = (float*)d_ws;

  // Pick NC (power of two) so carry + r + w fit in workspace.
  int NC = 128;
  while (NC > 1 &&
         ((size_t)NC * SC + 2 * SC) * sizeof(float) > ws_size) NC >>= 1;

  switch (L_ / NC) {
    case 32:   launch_all<32>(x, la, B, C, ws, y, stream); break;
    case 64:   launch_all<64>(x, la, B, C, ws, y, stream); break;
    case 128:  launch_all<128>(x, la, B, C, ws, y, stream); break;
    case 256:  launch_all<256>(x, la, B, C, ws, y, stream); break;
    case 512:  launch_all<512>(x, la, B, C, ws, y, stream); break;
    case 1024: launch_all<1024>(x, la, B, C, ws, y, stream); break;
    case 2048: launch_all<2048>(x, la, B, C, ws, y, stream); break;
    default:   launch_all<4096>(x, la, B, C, ws, y, stream); break;
  }
}